// Round 1
// baseline (1859.267 us; speedup 1.0000x reference)
//
#include <hip/hip_runtime.h>

typedef __bf16 bf16;
typedef bf16 bf16x8 __attribute__((ext_vector_type(8)));
typedef float f32x4 __attribute__((ext_vector_type(4)));

#define NJ 33
#define FD 64
#define NB_TOT 32768
#define NROWS (NB_TOT*NJ)        // 1,081,344
#define NPAIRS (NROWS/32)        // 33,792 pairs of 16-row tiles
#define GRID 512
#define WPB 8                    // waves per block (512 threads)
#define GWAVES (GRID*WPB)        // 4096 waves, ~8.25 pairs each

#define SELF4(j) ((unsigned)(j)*0x01010101u)

// neighbor ids packed 4x8bit, padded with self (loads past cnt are skipped)
__constant__ unsigned c_nbr[NJ] = {
  SELF4(0),SELF4(1),SELF4(2),SELF4(3),SELF4(4),SELF4(5),SELF4(6),SELF4(7),SELF4(8),SELF4(9),SELF4(10),
  (11u)|(12u<<8)|(23u<<16)|(13u<<24),
  (12u)|(11u<<8)|(24u<<16)|(14u<<24),
  (13u)|(11u<<8)|(15u<<16)|(13u<<24),
  (14u)|(12u<<8)|(16u<<16)|(14u<<24),
  (15u)|(13u<<8)|(15u<<16)|(15u<<24),
  (16u)|(14u<<8)|(16u<<16)|(16u<<24),
  SELF4(17),SELF4(18),SELF4(19),SELF4(20),SELF4(21),SELF4(22),
  (23u)|(11u<<8)|(24u<<16)|(25u<<24),
  (24u)|(12u<<8)|(23u<<16)|(26u<<24),
  (25u)|(23u<<8)|(27u<<16)|(25u<<24),
  (26u)|(24u<<8)|(28u<<16)|(26u<<24),
  (27u)|(25u<<8)|(27u<<16)|(27u<<24),
  (28u)|(26u<<8)|(28u<<16)|(28u<<24),
  SELF4(29),SELF4(30),SELF4(31),SELF4(32)
};
__constant__ int c_cnt[NJ] = {1,1,1,1,1,1,1,1,1,1,1,4,4,3,3,2,2,1,1,1,1,1,1,4,4,3,3,2,2,1,1,1,1};
__constant__ float c_winv[NJ] = {1.f,1.f,1.f,1.f,1.f,1.f,1.f,1.f,1.f,1.f,1.f,
  0.25f,0.25f,0.33333334f,0.33333334f,0.5f,0.5f,
  1.f,1.f,1.f,1.f,1.f,1.f,
  0.25f,0.25f,0.33333334f,0.33333334f,0.5f,0.5f,
  1.f,1.f,1.f,1.f};

#define MFMA(a,b,c) __builtin_amdgcn_mfma_f32_16x16x32_bf16((a),(b),(c),0,0,0)

__device__ static inline f32x4 splat4(float x){ f32x4 v = {x,x,x,x}; return v; }
__device__ static inline float fast_sigmoid(float x){
  return __builtin_amdgcn_rcpf(1.f + __expf(-x));
}
__device__ static inline float fast_tanh(float x){
  return 1.f - 2.f*__builtin_amdgcn_rcpf(1.f + __expf(2.f*x));
}

// LDS weight layout: rows 0..63 = msg_w, 64..255 = w_ih, 256..447 = w_hh (bf16).
// Each 64-elem row stored as 8 groups of 8 bf16, group g placed at g ^ (row&7)
// (XOR swizzle -> ~conflict-free B-fragment ds_read_b128).
__global__ __launch_bounds__(512, 4)
void skeleton_gnn(const float* __restrict__ feats, const float* __restrict__ vis,
                  const float* __restrict__ msgw, const float* __restrict__ msgb,
                  const float* __restrict__ wih,  const float* __restrict__ whh,
                  const float* __restrict__ bih,  const float* __restrict__ bhh,
                  float* __restrict__ out)
{
  __shared__ __align__(16) bf16 wlds[448*FD];        // 57,344 B (one copy per 8 waves)
  __shared__ __align__(16) bf16 scr[WPB][16*72];     // per-wave msgs C->A tile, 18,432 B

  const int tid  = threadIdx.x;
  const int wid  = tid >> 6;
  const int lane = tid & 63;
  const int m16  = lane & 15;
  const int quad = lane >> 4;

  // ---- stage weights into LDS (fp32 -> bf16, swizzled), coalesced 32B/thread
  for (int g = tid; g < 448*8; g += 512) {
    const int e = g >> 3, gr = g & 7;
    const float* src = (e < 64) ? (msgw + e*FD)
                     : (e < 256) ? (wih + (e-64)*FD)
                     : (whh + (e-256)*FD);
    const f32x4 v0 = *(const f32x4*)(src + gr*8);
    const f32x4 v1 = *(const f32x4*)(src + gr*8 + 4);
    bf16x8 v;
#pragma unroll
    for (int e2 = 0; e2 < 4; ++e2) { v[e2] = (bf16)v0[e2]; v[4+e2] = (bf16)v1[e2]; }
    *(bf16x8*)(wlds + e*FD + ((gr ^ (e & 7)) << 3)) = v;
  }

  // ---- per-lane bias registers (col = ct*16 + m16 in C-layout)
  float bias_rz[8], bias_in[4], bias_hn[4], bias_m[4];
#pragma unroll
  for (int ct = 0; ct < 8; ++ct)
    bias_rz[ct] = bih[ct*16+m16] + bhh[ct*16+m16];
#pragma unroll
  for (int ct = 0; ct < 4; ++ct) {
    const int c = 128 + ct*16 + m16;
    bias_in[ct] = bih[c];
    bias_hn[ct] = bhh[c];
    bias_m[ct]  = msgb[ct*16+m16];
  }
  __syncthreads();

  bf16* smsg = &scr[wid][0];      // msgs C-layout -> A-layout round-trip tile

  for (int p = blockIdx.x*WPB + wid; p < NPAIRS; p += GWAVES) {
    const int r0 = p*32;
    bf16x8 a_h[2][2], a_m[2][2], a_g[2][2];

    // ---- neighbor aggregation -> A-fragments (agg) + self row -> A-fragments (h)
#pragma unroll
    for (int s = 0; s < 2; ++s) {
      const int r = r0 + s*16 + m16;
      const int b = r / NJ;
      const int j = r - b*NJ;
      const unsigned nb = c_nbr[j];
      const float icw = c_winv[j];
      const int cnt = c_cnt[j];
      const float* fb = feats + (size_t)b*(NJ*FD);
      const float* vb = vis + b*NJ;

      // self row (always needed): feeds both a_h and acc
      const int j0 = nb & 255;
      const float w0 = vb[j0] * icw;
      float acc[2][8];
#pragma unroll
      for (int t = 0; t < 2; ++t) {
        const int k0 = t*32 + quad*8;
        const f32x4 s0 = *(const f32x4*)(fb + j0*FD + k0);
        const f32x4 s1 = *(const f32x4*)(fb + j0*FD + k0 + 4);
        bf16x8 ah;
#pragma unroll
        for (int e = 0; e < 4; ++e) {
          ah[e]   = (bf16)s0[e]; acc[t][e]   = w0*s0[e];
          ah[4+e] = (bf16)s1[e]; acc[t][4+e] = w0*s1[e];
        }
        a_h[s][t] = ah;
      }

      // real neighbors only: predicated loads (masked-off lanes issue nothing),
      // FMAs in a separate masked region so all loads batch before first use
      f32x4 nv[3][2][2]; float wv[3];
#pragma unroll
      for (int nn = 1; nn < 4; ++nn) {
        if (nn < cnt) {
          const int n = (nb >> (8*nn)) & 255;
          wv[nn-1] = vb[n] * icw;
#pragma unroll
          for (int t = 0; t < 2; ++t) {
            const int k0 = t*32 + quad*8;
            nv[nn-1][t][0] = *(const f32x4*)(fb + n*FD + k0);
            nv[nn-1][t][1] = *(const f32x4*)(fb + n*FD + k0 + 4);
          }
        }
      }
#pragma unroll
      for (int nn = 1; nn < 4; ++nn) {
        if (nn < cnt) {
#pragma unroll
          for (int t = 0; t < 2; ++t)
#pragma unroll
            for (int e = 0; e < 4; ++e) {
              acc[t][e]   += wv[nn-1]*nv[nn-1][t][0][e];
              acc[t][4+e] += wv[nn-1]*nv[nn-1][t][1][e];
            }
        }
      }
#pragma unroll
      for (int t = 0; t < 2; ++t) {
        bf16x8 am;
#pragma unroll
        for (int e = 0; e < 8; ++e) am[e] = (bf16)acc[t][e];
        a_m[s][t] = am;
      }
    }

    // ---- hoisted h reload (C-layout): rows are L1-hot from aggregation self loads;
    //      latency hides under the entire MFMA section below
    float hv[2][4][4];
#pragma unroll
    for (int s = 0; s < 2; ++s) {
      const size_t rowbase = (size_t)(r0 + s*16)*FD;
#pragma unroll
      for (int ct = 0; ct < 4; ++ct)
#pragma unroll
        for (int rg = 0; rg < 4; ++rg)
          hv[s][ct][rg] = feats[rowbase + (size_t)(quad*4+rg)*FD + ct*16 + m16];
    }

    // ---- msgs = agg @ msg_w^T + msg_b  (B-fragments shared across both 16-row tiles)
    f32x4 mc[2][4];
#pragma unroll
    for (int ct = 0; ct < 4; ++ct) { mc[0][ct] = splat4(bias_m[ct]); mc[1][ct] = splat4(bias_m[ct]); }
#pragma unroll
    for (int ct = 0; ct < 4; ++ct) {
      const int e = ct*16 + m16;
#pragma unroll
      for (int t = 0; t < 2; ++t) {
        const int g = t*4 + quad;
        const bf16x8 bw = *(const bf16x8*)(wlds + e*FD + ((g ^ (e & 7)) << 3));
        mc[0][ct] = MFMA(a_m[0][t], bw, mc[0][ct]);
        mc[1][ct] = MFMA(a_m[1][t], bw, mc[1][ct]);
      }
    }
    // C-layout -> A-layout via per-wave LDS tile (wave-private, in-order ds ops)
#pragma unroll
    for (int s = 0; s < 2; ++s) {
#pragma unroll
      for (int ct = 0; ct < 4; ++ct)
#pragma unroll
        for (int rg = 0; rg < 4; ++rg)
          smsg[(quad*4+rg)*72 + ct*16 + m16] = (bf16)mc[s][ct][rg];
#pragma unroll
      for (int t = 0; t < 2; ++t)
        a_g[s][t] = *(const bf16x8*)(smsg + m16*72 + t*32 + quad*8);
    }

    // ---- gi/gh GEMMs: r,z parts accumulate ih+hh into one acc; n parts kept split
    f32x4 arz[2][8], ain[2][4], ahn[2][4];
#pragma unroll
    for (int ct = 0; ct < 8; ++ct) { arz[0][ct] = splat4(bias_rz[ct]); arz[1][ct] = splat4(bias_rz[ct]); }
#pragma unroll
    for (int ct = 0; ct < 4; ++ct) {
      ain[0][ct] = splat4(bias_in[ct]); ain[1][ct] = splat4(bias_in[ct]);
      ahn[0][ct] = splat4(bias_hn[ct]); ahn[1][ct] = splat4(bias_hn[ct]);
    }
#pragma unroll
    for (int ct = 0; ct < 8; ++ct) {
      const int e1 = 64  + ct*16 + m16;   // w_ih rows 0..127  (r,z)
      const int e2 = 256 + ct*16 + m16;   // w_hh rows 0..127  (r,z)
#pragma unroll
      for (int t = 0; t < 2; ++t) {
        const int g = t*4 + quad;
        const bf16x8 b1 = *(const bf16x8*)(wlds + e1*FD + ((g ^ (e1 & 7)) << 3));
        arz[0][ct] = MFMA(a_g[0][t], b1, arz[0][ct]);
        arz[1][ct] = MFMA(a_g[1][t], b1, arz[1][ct]);
        const bf16x8 b2 = *(const bf16x8*)(wlds + e2*FD + ((g ^ (e2 & 7)) << 3));
        arz[0][ct] = MFMA(a_h[0][t], b2, arz[0][ct]);
        arz[1][ct] = MFMA(a_h[1][t], b2, arz[1][ct]);
      }
    }
#pragma unroll
    for (int ct = 0; ct < 4; ++ct) {
      const int e1 = 192 + ct*16 + m16;   // w_ih rows 128..191 (n)
      const int e2 = 384 + ct*16 + m16;   // w_hh rows 128..191 (n)
#pragma unroll
      for (int t = 0; t < 2; ++t) {
        const int g = t*4 + quad;
        const bf16x8 b1 = *(const bf16x8*)(wlds + e1*FD + ((g ^ (e1 & 7)) << 3));
        ain[0][ct] = MFMA(a_g[0][t], b1, ain[0][ct]);
        ain[1][ct] = MFMA(a_g[1][t], b1, ain[1][ct]);
        const bf16x8 b2 = *(const bf16x8*)(wlds + e2*FD + ((g ^ (e2 & 7)) << 3));
        ahn[0][ct] = MFMA(a_h[0][t], b2, ahn[0][ct]);
        ahn[1][ct] = MFMA(a_h[1][t], b2, ahn[1][ct]);
      }
    }

    // ---- GRU gates in C-layout; nontemporal fp32 stores (no RFO / write-allocate)
#pragma unroll
    for (int s = 0; s < 2; ++s) {
      const size_t rowbase = (size_t)(r0 + s*16)*FD;
#pragma unroll
      for (int ct = 0; ct < 4; ++ct) {
#pragma unroll
        for (int rg = 0; rg < 4; ++rg) {
          const float rr = fast_sigmoid(arz[s][ct][rg]);
          const float zz = fast_sigmoid(arz[s][ct+4][rg]);
          const float nvv = fast_tanh(ain[s][ct][rg] + rr*ahn[s][ct][rg]);
          const float o  = nvv + zz*(hv[s][ct][rg] - nvv);     // == (1-z)*n + z*h
          __builtin_nontemporal_store(o, &out[rowbase + (size_t)(quad*4+rg)*FD + ct*16 + m16]);
        }
      }
    }
  }
}

extern "C" void kernel_launch(void* const* d_in, const int* in_sizes, int n_in,
                              void* d_out, int out_size, void* d_ws, size_t ws_size,
                              hipStream_t stream) {
  (void)in_sizes; (void)n_in; (void)d_ws; (void)ws_size; (void)out_size;
  const float* feats = (const float*)d_in[0];
  const float* vis   = (const float*)d_in[1];
  const float* msgw  = (const float*)d_in[2];
  const float* msgb  = (const float*)d_in[3];
  const float* wih   = (const float*)d_in[4];
  const float* whh   = (const float*)d_in[5];
  const float* bih   = (const float*)d_in[6];
  const float* bhh   = (const float*)d_in[7];
  skeleton_gnn<<<GRID, 512, 0, stream>>>(feats, vis, msgw, msgb, wih, whh, bih, bhh, (float*)d_out);
}

// Round 3
// 1357.646 us; speedup vs baseline: 1.3695x; 1.3695x over previous
//
#include <hip/hip_runtime.h>

typedef __bf16 bf16;
typedef bf16 bf16x8 __attribute__((ext_vector_type(8)));
typedef float f32x4 __attribute__((ext_vector_type(4)));

#define NJ 33
#define FD 64
#define NB_TOT 32768
#define NROWS (NB_TOT*NJ)        // 1,081,344
#define NPAIRS (NROWS/32)        // 33,792 pairs of 16-row tiles
#define GRID 512
#define WPB 8                    // waves per block (512 threads)
#define GWAVES (GRID*WPB)        // 4096 waves, ~8.25 pairs each

#define SELF4(j) ((unsigned)(j)*0x01010101u)

// neighbor ids packed 4x8bit, padded with self (guarded loads skip the pads)
__constant__ unsigned c_nbr[NJ] = {
  SELF4(0),SELF4(1),SELF4(2),SELF4(3),SELF4(4),SELF4(5),SELF4(6),SELF4(7),SELF4(8),SELF4(9),SELF4(10),
  (11u)|(12u<<8)|(23u<<16)|(13u<<24),
  (12u)|(11u<<8)|(24u<<16)|(14u<<24),
  (13u)|(11u<<8)|(15u<<16)|(13u<<24),
  (14u)|(12u<<8)|(16u<<16)|(14u<<24),
  (15u)|(13u<<8)|(15u<<16)|(15u<<24),
  (16u)|(14u<<8)|(16u<<16)|(16u<<24),
  SELF4(17),SELF4(18),SELF4(19),SELF4(20),SELF4(21),SELF4(22),
  (23u)|(11u<<8)|(24u<<16)|(25u<<24),
  (24u)|(12u<<8)|(23u<<16)|(26u<<24),
  (25u)|(23u<<8)|(27u<<16)|(25u<<24),
  (26u)|(24u<<8)|(28u<<16)|(26u<<24),
  (27u)|(25u<<8)|(27u<<16)|(27u<<24),
  (28u)|(26u<<8)|(28u<<16)|(28u<<24),
  SELF4(29),SELF4(30),SELF4(31),SELF4(32)
};
__constant__ int c_cnt[NJ] = {1,1,1,1,1,1,1,1,1,1,1,4,4,3,3,2,2,1,1,1,1,1,1,4,4,3,3,2,2,1,1,1,1};
__constant__ float c_winv[NJ] = {1.f,1.f,1.f,1.f,1.f,1.f,1.f,1.f,1.f,1.f,1.f,
  0.25f,0.25f,0.33333334f,0.33333334f,0.5f,0.5f,
  1.f,1.f,1.f,1.f,1.f,1.f,
  0.25f,0.25f,0.33333334f,0.33333334f,0.5f,0.5f,
  1.f,1.f,1.f,1.f};

#define MFMA(a,b,c) __builtin_amdgcn_mfma_f32_16x16x32_bf16((a),(b),(c),0,0,0)

__device__ static inline f32x4 splat4(float x){ f32x4 v = {x,x,x,x}; return v; }
__device__ static inline float fast_sigmoid(float x){
  return __builtin_amdgcn_rcpf(1.f + __expf(-x));
}
__device__ static inline float fast_tanh(float x){
  return 1.f - 2.f*__builtin_amdgcn_rcpf(1.f + __expf(2.f*x));
}

// LDS weight layout: rows 0..63 = msg_w, 64..255 = w_ih, 256..447 = w_hh (bf16).
// Each 64-elem row stored as 8 groups of 8 bf16, group g placed at g ^ (row&7)
// (XOR swizzle -> ~conflict-free B-fragment ds_read_b128).
// 512-thread block: 8 waves share ONE weight copy -> LDS 75.8 KB -> 2 blocks/CU
// -> 16 waves/CU (vs 8 at 256-thread blocks).  launch_bounds(512,2): no VGPR cap
// pressure (round-1 lesson: forced caps + long live ranges = scratch spill).
__global__ __launch_bounds__(512, 2)
void skeleton_gnn(const float* __restrict__ feats, const float* __restrict__ vis,
                  const float* __restrict__ msgw, const float* __restrict__ msgb,
                  const float* __restrict__ wih,  const float* __restrict__ whh,
                  const float* __restrict__ bih,  const float* __restrict__ bhh,
                  float* __restrict__ out)
{
  __shared__ __align__(16) bf16 wlds[448*FD];        // 57,344 B (one copy per 8 waves)
  __shared__ __align__(16) bf16 scr[WPB][16*72];     // per-wave msgs C->A tile, 18,432 B

  const int tid  = threadIdx.x;
  const int wid  = tid >> 6;
  const int lane = tid & 63;
  const int m16  = lane & 15;
  const int quad = lane >> 4;

  // ---- stage weights into LDS (fp32 -> bf16, swizzled), coalesced 32B/thread
  for (int g = tid; g < 448*8; g += 512) {
    const int e = g >> 3, gr = g & 7;
    const float* src = (e < 64) ? (msgw + e*FD)
                     : (e < 256) ? (wih + (e-64)*FD)
                     : (whh + (e-256)*FD);
    const f32x4 v0 = *(const f32x4*)(src + gr*8);
    const f32x4 v1 = *(const f32x4*)(src + gr*8 + 4);
    bf16x8 v;
#pragma unroll
    for (int e2 = 0; e2 < 4; ++e2) { v[e2] = (bf16)v0[e2]; v[4+e2] = (bf16)v1[e2]; }
    *(bf16x8*)(wlds + e*FD + ((gr ^ (e & 7)) << 3)) = v;
  }

  // ---- per-lane bias registers (col = ct*16 + m16 in C-layout)
  float bias_rz[8], bias_in[4], bias_hn[4], bias_m[4];
#pragma unroll
  for (int ct = 0; ct < 8; ++ct)
    bias_rz[ct] = bih[ct*16+m16] + bhh[ct*16+m16];
#pragma unroll
  for (int ct = 0; ct < 4; ++ct) {
    const int c = 128 + ct*16 + m16;
    bias_in[ct] = bih[c];
    bias_hn[ct] = bhh[c];
    bias_m[ct]  = msgb[ct*16+m16];
  }
  __syncthreads();

  bf16* smsg = &scr[wid][0];      // msgs C-layout -> A-layout round-trip tile

  for (int p = blockIdx.x*WPB + wid; p < NPAIRS; p += GWAVES) {
    const int r0 = p*32;
    bf16x8 a_h[2][2], a_m[2][2], a_g[2][2];

    // ---- neighbor aggregation -> A-fragments (agg) + self row -> A-fragments (h)
#pragma unroll
    for (int s = 0; s < 2; ++s) {
      const int r = r0 + s*16 + m16;
      const int b = r / NJ;
      const int j = r - b*NJ;
      const unsigned nb = c_nbr[j];
      const float icw = c_winv[j];
      const int cnt = c_cnt[j];
      const float* fb = feats + (size_t)b*(NJ*FD);
      const float* vb = vis + b*NJ;
      int noff[4]; float wv[4];
#pragma unroll
      for (int nn = 0; nn < 4; ++nn) {
        const int n = (nb >> (8*nn)) & 255;
        noff[nn] = n*FD;
        wv[nn] = (nn < cnt) ? vb[n] * icw : 0.f;
      }
#pragma unroll
      for (int t = 0; t < 2; ++t) {
        const int k0 = t*32 + quad*8;
        const f32x4 s0 = *(const f32x4*)(fb + noff[0] + k0);       // self row
        const f32x4 s1 = *(const f32x4*)(fb + noff[0] + k0 + 4);
        bf16x8 ah;
        float acc[8];
#pragma unroll
        for (int e = 0; e < 4; ++e) {
          ah[e] = (bf16)s0[e];   acc[e]   = wv[0]*s0[e];
          ah[4+e] = (bf16)s1[e]; acc[4+e] = wv[0]*s1[e];
        }
        a_h[s][t] = ah;
        // real neighbors only: guarded load+FMA (masked-off lanes issue nothing,
        // short live ranges -> round-0 regalloc)
#pragma unroll
        for (int nn = 1; nn < 4; ++nn) {
          if (nn < cnt) {
            const f32x4 v0 = *(const f32x4*)(fb + noff[nn] + k0);
            const f32x4 v1 = *(const f32x4*)(fb + noff[nn] + k0 + 4);
#pragma unroll
            for (int e = 0; e < 4; ++e) {
              acc[e]   += wv[nn]*v0[e];
              acc[4+e] += wv[nn]*v1[e];
            }
          }
        }
        bf16x8 am;
#pragma unroll
        for (int e = 0; e < 8; ++e) am[e] = (bf16)acc[e];
        a_m[s][t] = am;
      }
    }

    // ---- msgs = agg @ msg_w^T + msg_b  (B-fragments shared across both 16-row tiles)
    f32x4 mc[2][4];
#pragma unroll
    for (int ct = 0; ct < 4; ++ct) { mc[0][ct] = splat4(bias_m[ct]); mc[1][ct] = splat4(bias_m[ct]); }
#pragma unroll
    for (int ct = 0; ct < 4; ++ct) {
      const int e = ct*16 + m16;
#pragma unroll
      for (int t = 0; t < 2; ++t) {
        const int g = t*4 + quad;
        const bf16x8 bw = *(const bf16x8*)(wlds + e*FD + ((g ^ (e & 7)) << 3));
        mc[0][ct] = MFMA(a_m[0][t], bw, mc[0][ct]);
        mc[1][ct] = MFMA(a_m[1][t], bw, mc[1][ct]);
      }
    }
    // C-layout -> A-layout via per-wave LDS tile (wave-private, in-order ds ops)
#pragma unroll
    for (int s = 0; s < 2; ++s) {
#pragma unroll
      for (int ct = 0; ct < 4; ++ct)
#pragma unroll
        for (int rg = 0; rg < 4; ++rg)
          smsg[(quad*4+rg)*72 + ct*16 + m16] = (bf16)mc[s][ct][rg];
#pragma unroll
      for (int t = 0; t < 2; ++t)
        a_g[s][t] = *(const bf16x8*)(smsg + m16*72 + t*32 + quad*8);
    }

    // ---- gi/gh GEMMs: r,z parts accumulate ih+hh into one acc; n parts kept split
    f32x4 arz[2][8], ain[2][4], ahn[2][4];
#pragma unroll
    for (int ct = 0; ct < 8; ++ct) { arz[0][ct] = splat4(bias_rz[ct]); arz[1][ct] = splat4(bias_rz[ct]); }
#pragma unroll
    for (int ct = 0; ct < 4; ++ct) {
      ain[0][ct] = splat4(bias_in[ct]); ain[1][ct] = splat4(bias_in[ct]);
      ahn[0][ct] = splat4(bias_hn[ct]); ahn[1][ct] = splat4(bias_hn[ct]);
    }
#pragma unroll
    for (int ct = 0; ct < 8; ++ct) {
      const int e1 = 64  + ct*16 + m16;   // w_ih rows 0..127  (r,z)
      const int e2 = 256 + ct*16 + m16;   // w_hh rows 0..127  (r,z)
#pragma unroll
      for (int t = 0; t < 2; ++t) {
        const int g = t*4 + quad;
        const bf16x8 b1 = *(const bf16x8*)(wlds + e1*FD + ((g ^ (e1 & 7)) << 3));
        arz[0][ct] = MFMA(a_g[0][t], b1, arz[0][ct]);
        arz[1][ct] = MFMA(a_g[1][t], b1, arz[1][ct]);
        const bf16x8 b2 = *(const bf16x8*)(wlds + e2*FD + ((g ^ (e2 & 7)) << 3));
        arz[0][ct] = MFMA(a_h[0][t], b2, arz[0][ct]);
        arz[1][ct] = MFMA(a_h[1][t], b2, arz[1][ct]);
      }
    }
#pragma unroll
    for (int ct = 0; ct < 4; ++ct) {
      const int e1 = 192 + ct*16 + m16;   // w_ih rows 128..191 (n)
      const int e2 = 384 + ct*16 + m16;   // w_hh rows 128..191 (n)
#pragma unroll
      for (int t = 0; t < 2; ++t) {
        const int g = t*4 + quad;
        const bf16x8 b1 = *(const bf16x8*)(wlds + e1*FD + ((g ^ (e1 & 7)) << 3));
        ain[0][ct] = MFMA(a_g[0][t], b1, ain[0][ct]);
        ain[1][ct] = MFMA(a_g[1][t], b1, ain[1][ct]);
        const bf16x8 b2 = *(const bf16x8*)(wlds + e2*FD + ((g ^ (e2 & 7)) << 3));
        ahn[0][ct] = MFMA(a_h[0][t], b2, ahn[0][ct]);
        ahn[1][ct] = MFMA(a_h[1][t], b2, ahn[1][ct]);
      }
    }

    // ---- GRU gates in C-layout; h reloaded fp32 from global (L1/L2 hit);
    //      fp32 stores directly at C-layout coords (16-lane x 4B = 64B segments)
#pragma unroll
    for (int s = 0; s < 2; ++s) {
      const size_t rowbase = (size_t)(r0 + s*16)*FD;
      float hv[4][4];
#pragma unroll
      for (int ct = 0; ct < 4; ++ct)
#pragma unroll
        for (int rg = 0; rg < 4; ++rg)
          hv[ct][rg] = feats[rowbase + (size_t)(quad*4+rg)*FD + ct*16 + m16];
#pragma unroll
      for (int ct = 0; ct < 4; ++ct) {
#pragma unroll
        for (int rg = 0; rg < 4; ++rg) {
          const float rr = fast_sigmoid(arz[s][ct][rg]);
          const float zz = fast_sigmoid(arz[s][ct+4][rg]);
          const float nv = fast_tanh(ain[s][ct][rg] + rr*ahn[s][ct][rg]);
          const float o  = nv + zz*(hv[ct][rg] - nv);     // == (1-z)*n + z*h
          out[rowbase + (size_t)(quad*4+rg)*FD + ct*16 + m16] = o;
        }
      }
    }
  }
}

extern "C" void kernel_launch(void* const* d_in, const int* in_sizes, int n_in,
                              void* d_out, int out_size, void* d_ws, size_t ws_size,
                              hipStream_t stream) {
  (void)in_sizes; (void)n_in; (void)d_ws; (void)ws_size; (void)out_size;
  const float* feats = (const float*)d_in[0];
  const float* vis   = (const float*)d_in[1];
  const float* msgw  = (const float*)d_in[2];
  const float* msgb  = (const float*)d_in[3];
  const float* wih   = (const float*)d_in[4];
  const float* whh   = (const float*)d_in[5];
  const float* bih   = (const float*)d_in[6];
  const float* bhh   = (const float*)d_in[7];
  skeleton_gnn<<<GRID, 512, 0, stream>>>(feats, vis, msgw, msgb, wih, whh, bih, bhh, (float*)d_out);
}

// Round 4
// 747.212 us; speedup vs baseline: 2.4883x; 1.8169x over previous
//
#include <hip/hip_runtime.h>

typedef __bf16 bf16;
typedef bf16 bf16x8 __attribute__((ext_vector_type(8)));
typedef float f32x4 __attribute__((ext_vector_type(4)));

#define NJ 33
#define FD 64
#define NB_TOT 32768
#define NROWS (NB_TOT*NJ)        // 1,081,344
#define NPAIRS (NROWS/32)        // 33,792 pairs of 16-row tiles
#define GRID 512
#define WPB 8                    // waves per block (512 threads)
#define GWAVES (GRID*WPB)        // 4096 waves, ~8.25 pairs each

#define SELF4(j) ((unsigned)(j)*0x01010101u)

// neighbor ids packed 4x8bit, padded with self (guarded loads skip the pads)
__constant__ unsigned c_nbr[NJ] = {
  SELF4(0),SELF4(1),SELF4(2),SELF4(3),SELF4(4),SELF4(5),SELF4(6),SELF4(7),SELF4(8),SELF4(9),SELF4(10),
  (11u)|(12u<<8)|(23u<<16)|(13u<<24),
  (12u)|(11u<<8)|(24u<<16)|(14u<<24),
  (13u)|(11u<<8)|(15u<<16)|(13u<<24),
  (14u)|(12u<<8)|(16u<<16)|(14u<<24),
  (15u)|(13u<<8)|(15u<<16)|(15u<<24),
  (16u)|(14u<<8)|(16u<<16)|(16u<<24),
  SELF4(17),SELF4(18),SELF4(19),SELF4(20),SELF4(21),SELF4(22),
  (23u)|(11u<<8)|(24u<<16)|(25u<<24),
  (24u)|(12u<<8)|(23u<<16)|(26u<<24),
  (25u)|(23u<<8)|(27u<<16)|(25u<<24),
  (26u)|(24u<<8)|(28u<<16)|(26u<<24),
  (27u)|(25u<<8)|(27u<<16)|(27u<<24),
  (28u)|(26u<<8)|(28u<<16)|(28u<<24),
  SELF4(29),SELF4(30),SELF4(31),SELF4(32)
};
__constant__ int c_cnt[NJ] = {1,1,1,1,1,1,1,1,1,1,1,4,4,3,3,2,2,1,1,1,1,1,1,4,4,3,3,2,2,1,1,1,1};
__constant__ float c_winv[NJ] = {1.f,1.f,1.f,1.f,1.f,1.f,1.f,1.f,1.f,1.f,1.f,
  0.25f,0.25f,0.33333334f,0.33333334f,0.5f,0.5f,
  1.f,1.f,1.f,1.f,1.f,1.f,
  0.25f,0.25f,0.33333334f,0.33333334f,0.5f,0.5f,
  1.f,1.f,1.f,1.f};

#define MFMA(a,b,c) __builtin_amdgcn_mfma_f32_16x16x32_bf16((a),(b),(c),0,0,0)

__device__ static inline f32x4 splat4(float x){ f32x4 v = {x,x,x,x}; return v; }
__device__ static inline float fast_sigmoid(float x){
  return __builtin_amdgcn_rcpf(1.f + __expf(-x));
}
__device__ static inline float fast_tanh(float x){
  return 1.f - 2.f*__builtin_amdgcn_rcpf(1.f + __expf(2.f*x));
}

// LDS weight layout: rows 0..63 = msg_w, 64..255 = w_ih, 256..447 = w_hh (bf16).
// Each 64-elem row stored as 8 groups of 8 bf16, group g placed at g ^ (row&7)
// (XOR swizzle -> ~conflict-free B-fragment ds_read_b128).
//
// Round-4 change: A-fragments (agg msg, self h, transformed msgs) live in
// per-wave LDS tiles instead of registers.  Rationale (R0/R3 counters):
// total regs/lane ~256 (128 arch + 128 accum) -> reg-capped at 1 block/CU,
// and holding 48 frag dwords across phases spilled ~650 MB write + ~900 MB
// read of scratch per pass (FETCH 1.75 GB vs 0.77 GB issued; WRITE 932 MB
// vs 276 MB output).  Since occupancy is reg-capped at 1 block/CU, LDS up
// to 160 KB is free: tiles cost 73.7 KB -> total 128 KiB.
__global__ __launch_bounds__(512, 2)
void skeleton_gnn(const float* __restrict__ feats, const float* __restrict__ vis,
                  const float* __restrict__ msgw, const float* __restrict__ msgb,
                  const float* __restrict__ wih,  const float* __restrict__ whh,
                  const float* __restrict__ bih,  const float* __restrict__ bhh,
                  float* __restrict__ out)
{
  __shared__ __align__(16) bf16 wlds[448*FD];          // 57,344 B (one copy per 8 waves)
  __shared__ __align__(16) bf16 tiles[WPB][2][32*72];  // per wave: [0]=msg/agg tile, [1]=h tile; 73,728 B

  const int tid  = threadIdx.x;
  const int wid  = tid >> 6;
  const int lane = tid & 63;
  const int m16  = lane & 15;
  const int quad = lane >> 4;

  // ---- stage weights into LDS (fp32 -> bf16, swizzled), coalesced 32B/thread
  for (int g = tid; g < 448*8; g += 512) {
    const int e = g >> 3, gr = g & 7;
    const float* src = (e < 64) ? (msgw + e*FD)
                     : (e < 256) ? (wih + (e-64)*FD)
                     : (whh + (e-256)*FD);
    const f32x4 v0 = *(const f32x4*)(src + gr*8);
    const f32x4 v1 = *(const f32x4*)(src + gr*8 + 4);
    bf16x8 v;
#pragma unroll
    for (int e2 = 0; e2 < 4; ++e2) { v[e2] = (bf16)v0[e2]; v[4+e2] = (bf16)v1[e2]; }
    *(bf16x8*)(wlds + e*FD + ((gr ^ (e & 7)) << 3)) = v;
  }

  // ---- per-lane bias registers (col = ct*16 + m16 in C-layout)
  float bias_rz[8], bias_in[4], bias_hn[4], bias_m[4];
#pragma unroll
  for (int ct = 0; ct < 8; ++ct)
    bias_rz[ct] = bih[ct*16+m16] + bhh[ct*16+m16];
#pragma unroll
  for (int ct = 0; ct < 4; ++ct) {
    const int c = 128 + ct*16 + m16;
    bias_in[ct] = bih[c];
    bias_hn[ct] = bhh[c];
    bias_m[ct]  = msgb[ct*16+m16];
  }
  __syncthreads();

  bf16* tm = &tiles[wid][0][0];   // agg msgs, then transformed msgs (A-layout rows)
  bf16* th = &tiles[wid][1][0];   // self h rows (A-layout rows)

  // A-fragment address for tile-half s, k-block t (read AND write use this):
  // lane m16 = row, quad selects 8-col group:  (s*16+m16)*72 + t*32 + quad*8
  #define FRAG_OFF(s,t) (((s)*16 + m16)*72 + (t)*32 + quad*8)

  for (int p = blockIdx.x*WPB + wid; p < NPAIRS; p += GWAVES) {
    const int r0 = p*32;

    // ---- neighbor aggregation -> tm rows ; self rows -> th (bf16, A-layout)
#pragma unroll
    for (int s = 0; s < 2; ++s) {
      const int r = r0 + s*16 + m16;
      const int b = r / NJ;
      const int j = r - b*NJ;
      const unsigned nb = c_nbr[j];
      const float icw = c_winv[j];
      const int cnt = c_cnt[j];
      const float* fb = feats + (size_t)b*(NJ*FD);
      const float* vb = vis + b*NJ;
      int noff[4]; float wv[4];
#pragma unroll
      for (int nn = 0; nn < 4; ++nn) {
        const int n = (nb >> (8*nn)) & 255;
        noff[nn] = n*FD;
        wv[nn] = (nn < cnt) ? vb[n] * icw : 0.f;
      }
#pragma unroll
      for (int t = 0; t < 2; ++t) {
        const int k0 = t*32 + quad*8;
        const f32x4 s0 = *(const f32x4*)(fb + noff[0] + k0);       // self row
        const f32x4 s1 = *(const f32x4*)(fb + noff[0] + k0 + 4);
        bf16x8 ah;
        float acc[8];
#pragma unroll
        for (int e = 0; e < 4; ++e) {
          ah[e] = (bf16)s0[e];   acc[e]   = wv[0]*s0[e];
          ah[4+e] = (bf16)s1[e]; acc[4+e] = wv[0]*s1[e];
        }
        *(bf16x8*)(th + FRAG_OFF(s,t)) = ah;                       // h -> LDS, done
        // real neighbors only: guarded load+FMA (masked-off lanes issue nothing)
#pragma unroll
        for (int nn = 1; nn < 4; ++nn) {
          if (nn < cnt) {
            const f32x4 v0 = *(const f32x4*)(fb + noff[nn] + k0);
            const f32x4 v1 = *(const f32x4*)(fb + noff[nn] + k0 + 4);
#pragma unroll
            for (int e = 0; e < 4; ++e) {
              acc[e]   += wv[nn]*v0[e];
              acc[4+e] += wv[nn]*v1[e];
            }
          }
        }
        bf16x8 am;
#pragma unroll
        for (int e = 0; e < 8; ++e) am[e] = (bf16)acc[e];
        *(bf16x8*)(tm + FRAG_OFF(s,t)) = am;                       // agg -> LDS
      }
    }

    // ---- msgs = agg @ msg_w^T + msg_b : load agg A-frags transiently
    {
      bf16x8 amf[2][2];
#pragma unroll
      for (int s = 0; s < 2; ++s)
#pragma unroll
        for (int t = 0; t < 2; ++t)
          amf[s][t] = *(const bf16x8*)(tm + FRAG_OFF(s,t));

      f32x4 mc[2][4];
#pragma unroll
      for (int ct = 0; ct < 4; ++ct) { mc[0][ct] = splat4(bias_m[ct]); mc[1][ct] = splat4(bias_m[ct]); }
#pragma unroll
      for (int ct = 0; ct < 4; ++ct) {
        const int e = ct*16 + m16;
#pragma unroll
        for (int t = 0; t < 2; ++t) {
          const int g = t*4 + quad;
          const bf16x8 bw = *(const bf16x8*)(wlds + e*FD + ((g ^ (e & 7)) << 3));
          mc[0][ct] = MFMA(amf[0][t], bw, mc[0][ct]);
          mc[1][ct] = MFMA(amf[1][t], bw, mc[1][ct]);
        }
      }
      // C-layout -> A-layout: write msgs back into tm (agg data fully consumed)
#pragma unroll
      for (int s = 0; s < 2; ++s)
#pragma unroll
        for (int ct = 0; ct < 4; ++ct)
#pragma unroll
          for (int rg = 0; rg < 4; ++rg)
            tm[(s*16 + quad*4 + rg)*72 + ct*16 + m16] = (bf16)mc[s][ct][rg];
    }

    // ---- gi/gh GEMMs: load msg + h A-frags transiently (live only this phase)
    bf16x8 ag[2][2], ahf[2][2];
#pragma unroll
    for (int s = 0; s < 2; ++s)
#pragma unroll
      for (int t = 0; t < 2; ++t) {
        ag[s][t]  = *(const bf16x8*)(tm + FRAG_OFF(s,t));
        ahf[s][t] = *(const bf16x8*)(th + FRAG_OFF(s,t));
      }

    f32x4 arz[2][8], ain[2][4], ahn[2][4];
#pragma unroll
    for (int ct = 0; ct < 8; ++ct) { arz[0][ct] = splat4(bias_rz[ct]); arz[1][ct] = splat4(bias_rz[ct]); }
#pragma unroll
    for (int ct = 0; ct < 4; ++ct) {
      ain[0][ct] = splat4(bias_in[ct]); ain[1][ct] = splat4(bias_in[ct]);
      ahn[0][ct] = splat4(bias_hn[ct]); ahn[1][ct] = splat4(bias_hn[ct]);
    }
#pragma unroll
    for (int ct = 0; ct < 8; ++ct) {
      const int e1 = 64  + ct*16 + m16;   // w_ih rows 0..127  (r,z)
      const int e2 = 256 + ct*16 + m16;   // w_hh rows 0..127  (r,z)
#pragma unroll
      for (int t = 0; t < 2; ++t) {
        const int g = t*4 + quad;
        const bf16x8 b1 = *(const bf16x8*)(wlds + e1*FD + ((g ^ (e1 & 7)) << 3));
        arz[0][ct] = MFMA(ag[0][t], b1, arz[0][ct]);
        arz[1][ct] = MFMA(ag[1][t], b1, arz[1][ct]);
        const bf16x8 b2 = *(const bf16x8*)(wlds + e2*FD + ((g ^ (e2 & 7)) << 3));
        arz[0][ct] = MFMA(ahf[0][t], b2, arz[0][ct]);
        arz[1][ct] = MFMA(ahf[1][t], b2, arz[1][ct]);
      }
    }
#pragma unroll
    for (int ct = 0; ct < 4; ++ct) {
      const int e1 = 192 + ct*16 + m16;   // w_ih rows 128..191 (n)
      const int e2 = 384 + ct*16 + m16;   // w_hh rows 128..191 (n)
#pragma unroll
      for (int t = 0; t < 2; ++t) {
        const int g = t*4 + quad;
        const bf16x8 b1 = *(const bf16x8*)(wlds + e1*FD + ((g ^ (e1 & 7)) << 3));
        ain[0][ct] = MFMA(ag[0][t], b1, ain[0][ct]);
        ain[1][ct] = MFMA(ag[1][t], b1, ain[1][ct]);
        const bf16x8 b2 = *(const bf16x8*)(wlds + e2*FD + ((g ^ (e2 & 7)) << 3));
        ahn[0][ct] = MFMA(ahf[0][t], b2, ahn[0][ct]);
        ahn[1][ct] = MFMA(ahf[1][t], b2, ahn[1][ct]);
      }
    }

    // ---- GRU gates in C-layout; h reloaded fp32 from global (exact);
    //      fp32 stores directly at C-layout coords (16-lane x 4B = 64B segments)
#pragma unroll
    for (int s = 0; s < 2; ++s) {
      const size_t rowbase = (size_t)(r0 + s*16)*FD;
      float hv[4][4];
#pragma unroll
      for (int ct = 0; ct < 4; ++ct)
#pragma unroll
        for (int rg = 0; rg < 4; ++rg)
          hv[ct][rg] = feats[rowbase + (size_t)(quad*4+rg)*FD + ct*16 + m16];
#pragma unroll
      for (int ct = 0; ct < 4; ++ct) {
#pragma unroll
        for (int rg = 0; rg < 4; ++rg) {
          const float rr = fast_sigmoid(arz[s][ct][rg]);
          const float zz = fast_sigmoid(arz[s][ct+4][rg]);
          const float nv = fast_tanh(ain[s][ct][rg] + rr*ahn[s][ct][rg]);
          const float o  = nv + zz*(hv[ct][rg] - nv);     // == (1-z)*n + z*h
          out[rowbase + (size_t)(quad*4+rg)*FD + ct*16 + m16] = o;
        }
      }
    }
  }
  #undef FRAG_OFF
}

extern "C" void kernel_launch(void* const* d_in, const int* in_sizes, int n_in,
                              void* d_out, int out_size, void* d_ws, size_t ws_size,
                              hipStream_t stream) {
  (void)in_sizes; (void)n_in; (void)d_ws; (void)ws_size; (void)out_size;
  const float* feats = (const float*)d_in[0];
  const float* vis   = (const float*)d_in[1];
  const float* msgw  = (const float*)d_in[2];
  const float* msgb  = (const float*)d_in[3];
  const float* wih   = (const float*)d_in[4];
  const float* whh   = (const float*)d_in[5];
  const float* bih   = (const float*)d_in[6];
  const float* bhh   = (const float*)d_in[7];
  skeleton_gnn<<<GRID, 512, 0, stream>>>(feats, vis, msgw, msgb, wih, whh, bih, bhh, (float*)d_out);
}